// Round 1
// baseline (415.992 us; speedup 1.0000x reference)
//
#include <hip/hip_runtime.h>
#include <math.h>

#define TT 4096
#define DM 1024
#define BB 4
#define BT (BB * TT)

// ws layout (floats/ints):
//   Q   : float[BT*2]            @ byte 0
//   K   : float[BT*2]            @ byte BT*2*4
//   idx : int[BT]                @ byte BT*4*4
//   rep : int[BT]                @ byte BT*4*4 + BT*4
// total = BT*4*4 + BT*8 = 16384*24 = 393216 bytes

#define SENTINEL 0x7fffffff

// ---------- Kernel 1: Q,K projection. One block (256 thr) per (b,t) row ----------
__global__ __launch_bounds__(256) void qk_kernel(const float* __restrict__ x,
                                                 const float* __restrict__ wq,
                                                 const float* __restrict__ wk,
                                                 float* __restrict__ Q,
                                                 float* __restrict__ K) {
    const int row = blockIdx.x;
    const int tid = threadIdx.x;

    const float4 xv = ((const float4*)(x + (size_t)row * DM))[tid];
    const float4 a0 = ((const float4*)(wq))[tid];         // W_Q row 0
    const float4 a1 = ((const float4*)(wq + DM))[tid];    // W_Q row 1
    const float4 b0 = ((const float4*)(wk))[tid];         // W_K row 0
    const float4 b1 = ((const float4*)(wk + DM))[tid];    // W_K row 1

    float s0 = xv.x * a0.x + xv.y * a0.y + xv.z * a0.z + xv.w * a0.w;
    float s1 = xv.x * a1.x + xv.y * a1.y + xv.z * a1.z + xv.w * a1.w;
    float s2 = xv.x * b0.x + xv.y * b0.y + xv.z * b0.z + xv.w * b0.w;
    float s3 = xv.x * b1.x + xv.y * b1.y + xv.z * b1.z + xv.w * b1.w;

    // wave (64-lane) reduction
    #pragma unroll
    for (int off = 32; off > 0; off >>= 1) {
        s0 += __shfl_down(s0, off);
        s1 += __shfl_down(s1, off);
        s2 += __shfl_down(s2, off);
        s3 += __shfl_down(s3, off);
    }
    __shared__ float red[4][4];
    const int wave = tid >> 6, lane = tid & 63;
    if (lane == 0) { red[wave][0] = s0; red[wave][1] = s1; red[wave][2] = s2; red[wave][3] = s3; }
    __syncthreads();
    if (tid == 0) {
        float q0 = red[0][0] + red[1][0] + red[2][0] + red[3][0];
        float q1 = red[0][1] + red[1][1] + red[2][1] + red[3][1];
        float k0 = red[0][2] + red[1][2] + red[2][2] + red[3][2];
        float k1 = red[0][3] + red[1][3] + red[2][3] + red[3][3];
        Q[row * 2 + 0] = q0; Q[row * 2 + 1] = q1;
        K[row * 2 + 0] = k0; K[row * 2 + 1] = k1;
    }
}

// ---------- Kernel 2: init rep[] sentinel ----------
__global__ __launch_bounds__(256) void init_rep_kernel(int* __restrict__ rep) {
    rep[blockIdx.x * 256 + threadIdx.x] = SENTINEL;
}

// ---------- Kernel 3: causal argmax. K[b] in LDS, one thread per t ----------
__global__ __launch_bounds__(256) void argmax_kernel(const float* __restrict__ Q,
                                                     const float* __restrict__ K,
                                                     int* __restrict__ idx,
                                                     int* __restrict__ rep) {
    __shared__ float k0s[TT];
    __shared__ float k1s[TT];
    const int b = blockIdx.x >> 4;               // 16 blocks per batch
    const int tbase = (blockIdx.x & 15) * 256;
    const int tid = threadIdx.x;

    const float2* kb = (const float2*)(K + (size_t)b * TT * 2);
    for (int i = tid; i < TT; i += 256) {
        float2 kv = kb[i];
        k0s[i] = kv.x; k1s[i] = kv.y;
    }
    __syncthreads();

    const int t = tbase + tid;
    const float q0 = Q[(b * TT + t) * 2 + 0];
    const float q1 = Q[(b * TT + t) * 2 + 1];

    float best = -INFINITY;
    int bi = 0;
    const int n = t + 1;
    const int n4 = n & ~3;
    int s = 0;
    for (; s < n4; s += 4) {
        // same-address LDS reads across the wave -> broadcast, no conflict
        const float4 kk0 = *(const float4*)(k0s + s);
        const float4 kk1 = *(const float4*)(k1s + s);
        const float sc0 = q0 * kk0.x + q1 * kk1.x;
        const float sc1 = q0 * kk0.y + q1 * kk1.y;
        const float sc2 = q0 * kk0.z + q1 * kk1.z;
        const float sc3 = q0 * kk0.w + q1 * kk1.w;
        // ascending order + strict '>' == numpy first-occurrence argmax
        if (sc0 > best) { best = sc0; bi = s + 0; }
        if (sc1 > best) { best = sc1; bi = s + 1; }
        if (sc2 > best) { best = sc2; bi = s + 2; }
        if (sc3 > best) { best = sc3; bi = s + 3; }
    }
    for (; s < n; ++s) {
        const float sc = q0 * k0s[s] + q1 * k1s[s];
        if (sc > best) { best = sc; bi = s; }
    }
    idx[b * TT + t] = bi;
    atomicMin(&rep[b * TT + bi], t);   // earliest t using this source row
}

// ---------- Kernel 4: V-row for each unique argmax target, written to out[b, rep_t] ----------
__global__ __launch_bounds__(256) void vrow_kernel(const float* __restrict__ x,
                                                   const float* __restrict__ wv,
                                                   const int* __restrict__ rep,
                                                   float* __restrict__ out) {
    const int bs = blockIdx.x;        // b*TT + s
    const int r = rep[bs];
    if (r == SENTINEL) return;        // s never selected -> nothing to do
    const int b = bs >> 12;

    __shared__ float xs[DM];
    const int tid = threadIdx.x;
    ((float4*)xs)[tid] = ((const float4*)(x + (size_t)bs * DM))[tid];
    __syncthreads();

    const int wave = tid >> 6, lane = tid & 63;
    float* orow = out + ((size_t)(b * TT + r)) * DM;

    // each wave computes output elements e = wave, wave+4, ... (whole-wave dot + shuffle reduce)
    for (int e = wave; e < DM; e += 4) {
        const float4* wr = (const float4*)(wv + (size_t)e * DM);
        float sum = 0.f;
        #pragma unroll
        for (int k = 0; k < 4; ++k) {
            const float4 w  = wr[lane + 64 * k];               // coalesced
            const float4 xx = ((const float4*)xs)[lane + 64 * k];
            sum += w.x * xx.x + w.y * xx.y + w.z * xx.z + w.w * xx.w;
        }
        #pragma unroll
        for (int off = 32; off > 0; off >>= 1) sum += __shfl_down(sum, off);
        if (lane == 0) orow[e] = sum;
    }
}

// ---------- Kernel 5: broadcast representative rows to all t ----------
__global__ __launch_bounds__(256) void gather_kernel(const int* __restrict__ idx,
                                                     const int* __restrict__ rep,
                                                     float* __restrict__ out) {
    const int bt = blockIdx.x;
    const int b = bt >> 12, t = bt & (TT - 1);
    const int s = idx[bt];
    const int r = rep[b * TT + s];
    if (r == t) return;               // representative row already holds the value
    const float4* src = (const float4*)(out + ((size_t)(b * TT + r)) * DM);
    float4* dst = (float4*)(out + (size_t)bt * DM);
    dst[threadIdx.x] = src[threadIdx.x];
}

extern "C" void kernel_launch(void* const* d_in, const int* in_sizes, int n_in,
                              void* d_out, int out_size, void* d_ws, size_t ws_size,
                              hipStream_t stream) {
    const float* x  = (const float*)d_in[0];
    const float* wq = (const float*)d_in[1];
    const float* wk = (const float*)d_in[2];
    const float* wv = (const float*)d_in[3];
    // d_in[4] = causal_mask (bool) — semantics baked into the argmax loop bound.
    float* out = (float*)d_out;

    char* ws = (char*)d_ws;
    float* Q   = (float*)(ws);
    float* K   = (float*)(ws + (size_t)BT * 2 * sizeof(float));
    int*   idx = (int*)  (ws + (size_t)BT * 4 * sizeof(float));
    int*   rep = (int*)  (ws + (size_t)BT * 4 * sizeof(float) + (size_t)BT * sizeof(int));

    qk_kernel<<<BT, 256, 0, stream>>>(x, wq, wk, Q, K);
    init_rep_kernel<<<BT / 256, 256, 0, stream>>>(rep);
    argmax_kernel<<<BT / 256, 256, 0, stream>>>(Q, K, idx, rep);
    vrow_kernel<<<BT, 256, 0, stream>>>(x, wv, rep, out);
    gather_kernel<<<BT, 256, 0, stream>>>(idx, rep, out);
}

// Round 2
// 242.606 us; speedup vs baseline: 1.7147x; 1.7147x over previous
//
#include <hip/hip_runtime.h>
#include <math.h>

#define TT 4096
#define DM 1024
#define BB 4
#define BT (BB * TT)
#define SENTINEL 0x7fffffff
#define SPLIT 8   // blocks per unique V-row

// ws layout (bytes):
//   Q    : float[BT*2]  @ 0        (131072)
//   K    : float[BT*2]  @ 131072   (131072)  (interleaved k0,k1 pairs)
//   idx  : int[BT]      @ 262144   (65536)
//   rep  : int[BT]      @ 327680   (65536)
//   list : int[BT]      @ 393216   (65536)
//   cnt  : int          @ 458752   (4)

// ---------- Kernel 1: Q,K projection. One block (256 thr) per (b,t) row ----------
__global__ __launch_bounds__(256) void qk_kernel(const float* __restrict__ x,
                                                 const float* __restrict__ wq,
                                                 const float* __restrict__ wk,
                                                 float* __restrict__ Q,
                                                 float* __restrict__ K) {
    const int row = blockIdx.x;
    const int tid = threadIdx.x;

    const float4 xv = ((const float4*)(x + (size_t)row * DM))[tid];
    const float4 a0 = ((const float4*)(wq))[tid];
    const float4 a1 = ((const float4*)(wq + DM))[tid];
    const float4 b0 = ((const float4*)(wk))[tid];
    const float4 b1 = ((const float4*)(wk + DM))[tid];

    float s0 = xv.x * a0.x + xv.y * a0.y + xv.z * a0.z + xv.w * a0.w;
    float s1 = xv.x * a1.x + xv.y * a1.y + xv.z * a1.z + xv.w * a1.w;
    float s2 = xv.x * b0.x + xv.y * b0.y + xv.z * b0.z + xv.w * b0.w;
    float s3 = xv.x * b1.x + xv.y * b1.y + xv.z * b1.z + xv.w * b1.w;

    #pragma unroll
    for (int off = 32; off > 0; off >>= 1) {
        s0 += __shfl_down(s0, off);
        s1 += __shfl_down(s1, off);
        s2 += __shfl_down(s2, off);
        s3 += __shfl_down(s3, off);
    }
    __shared__ float red[4][4];
    const int wave = tid >> 6, lane = tid & 63;
    if (lane == 0) { red[wave][0] = s0; red[wave][1] = s1; red[wave][2] = s2; red[wave][3] = s3; }
    __syncthreads();
    if (tid == 0) {
        Q[row * 2 + 0] = red[0][0] + red[1][0] + red[2][0] + red[3][0];
        Q[row * 2 + 1] = red[0][1] + red[1][1] + red[2][1] + red[3][1];
        K[row * 2 + 0] = red[0][2] + red[1][2] + red[2][2] + red[3][2];
        K[row * 2 + 1] = red[0][3] + red[1][3] + red[2][3] + red[3][3];
    }
}

// ---------- Kernel 2: init rep[] sentinel + zero count ----------
__global__ __launch_bounds__(256) void init_rep_kernel(int* __restrict__ rep,
                                                       int* __restrict__ cnt) {
    rep[blockIdx.x * 256 + threadIdx.x] = SENTINEL;
    if (blockIdx.x == 0 && threadIdx.x == 0) cnt[0] = 0;
}

// ---------- Kernel 3: causal argmax. One WAVE per t (4096 blocks), K[b] in LDS ----------
__global__ __launch_bounds__(256) void argmax_kernel(const float* __restrict__ Q,
                                                     const float* __restrict__ K,
                                                     int* __restrict__ idx,
                                                     int* __restrict__ rep,
                                                     int* __restrict__ list,
                                                     int* __restrict__ cnt) {
    __shared__ float2 ks[TT];   // 32 KB
    const int b  = blockIdx.x >> 10;          // 1024 blocks per batch
    const int tg = blockIdx.x & 1023;
    const int tid = threadIdx.x;

    const float2* kb = (const float2*)(K + (size_t)b * TT * 2);
    for (int i = tid; i < TT; i += 256) ks[i] = kb[i];
    __syncthreads();

    const int wave = tid >> 6, lane = tid & 63;
    const int t = tg * 4 + wave;
    const float2 q = ((const float2*)Q)[b * TT + t];

    // lane-strided ascending scan with strict '>' keeps lane-local earliest max
    float best = -INFINITY;
    int bi = 0x7fffffff;
    for (int s = lane; s <= t; s += 64) {
        const float2 kv = ks[s];
        const float sc = q.x * kv.x + q.y * kv.y;
        if (sc > best) { best = sc; bi = s; }
    }
    // cross-lane argmax, first-occurrence tie-break (smaller index wins on equal)
    #pragma unroll
    for (int off = 32; off > 0; off >>= 1) {
        const float ov = __shfl_down(best, off);
        const int   oi = __shfl_down(bi, off);
        if (ov > best || (ov == best && oi < bi)) { best = ov; bi = oi; }
    }
    if (lane == 0) {
        idx[b * TT + t] = bi;
        const int old = atomicMin(&rep[b * TT + bi], t);
        if (old == SENTINEL) {                 // first claimant appends to work list
            const int p = atomicAdd(cnt, 1);
            list[p] = b * TT + bi;
        }
    }
}

// ---------- Kernel 4: V-rows for unique targets. Grid-stride over count*SPLIT ----------
__global__ __launch_bounds__(256) void vrow_kernel(const float* __restrict__ x,
                                                   const float* __restrict__ wv,
                                                   const int* __restrict__ rep,
                                                   const int* __restrict__ list,
                                                   const int* __restrict__ cnt,
                                                   float* __restrict__ out) {
    __shared__ float xs[DM];
    const int total = cnt[0] * SPLIT;
    const int tid = threadIdx.x;
    const int wave = tid >> 6, lane = tid & 63;

    for (int w = blockIdx.x; w < total; w += gridDim.x) {
        const int li = w >> 3;          // which unique row
        const int p  = w & (SPLIT - 1); // which 128-wide output slice
        const int bs = list[li];
        const int b  = bs >> 12;
        const int r  = rep[bs];

        __syncthreads();                // protect xs across grid-stride iterations
        ((float4*)xs)[tid] = ((const float4*)(x + (size_t)bs * DM))[tid];
        __syncthreads();

        // x-row slice cached in registers (same for all 8 groups)
        const float4 xr0 = ((const float4*)xs)[lane];
        const float4 xr1 = ((const float4*)xs)[lane + 64];
        const float4 xr2 = ((const float4*)xs)[lane + 128];
        const float4 xr3 = ((const float4*)xs)[lane + 192];

        float* orow = out + ((size_t)(b * TT + r)) * DM;
        const int ebase = p * 128 + wave * 32;

        for (int g = 0; g < 8; ++g) {
            const int e = ebase + g * 4;
            const float4* w0 = (const float4*)(wv + (size_t)(e + 0) * DM);
            const float4* w1 = (const float4*)(wv + (size_t)(e + 1) * DM);
            const float4* w2 = (const float4*)(wv + (size_t)(e + 2) * DM);
            const float4* w3 = (const float4*)(wv + (size_t)(e + 3) * DM);

            float s0 = 0.f, s1 = 0.f, s2 = 0.f, s3 = 0.f;
            #pragma unroll
            for (int k = 0; k < 4; ++k) {
                const float4 xx = (k == 0) ? xr0 : (k == 1) ? xr1 : (k == 2) ? xr2 : xr3;
                const float4 a = w0[lane + 64 * k];
                const float4 bq = w1[lane + 64 * k];
                const float4 c = w2[lane + 64 * k];
                const float4 d = w3[lane + 64 * k];
                s0 += a.x * xx.x + a.y * xx.y + a.z * xx.z + a.w * xx.w;
                s1 += bq.x * xx.x + bq.y * xx.y + bq.z * xx.z + bq.w * xx.w;
                s2 += c.x * xx.x + c.y * xx.y + c.z * xx.z + c.w * xx.w;
                s3 += d.x * xx.x + d.y * xx.y + d.z * xx.z + d.w * xx.w;
            }
            #pragma unroll
            for (int off = 32; off > 0; off >>= 1) {
                s0 += __shfl_down(s0, off);
                s1 += __shfl_down(s1, off);
                s2 += __shfl_down(s2, off);
                s3 += __shfl_down(s3, off);
            }
            if (lane == 0) *(float4*)(orow + e) = make_float4(s0, s1, s2, s3);
        }
    }
}

// ---------- Kernel 5: broadcast representative rows to all t ----------
__global__ __launch_bounds__(256) void gather_kernel(const int* __restrict__ idx,
                                                     const int* __restrict__ rep,
                                                     float* __restrict__ out) {
    const int bt = blockIdx.x;
    const int b = bt >> 12, t = bt & (TT - 1);
    const int s = idx[bt];
    const int r = rep[b * TT + s];
    if (r == t) return;
    const float4* src = (const float4*)(out + ((size_t)(b * TT + r)) * DM);
    float4* dst = (float4*)(out + (size_t)bt * DM);
    dst[threadIdx.x] = src[threadIdx.x];
}

extern "C" void kernel_launch(void* const* d_in, const int* in_sizes, int n_in,
                              void* d_out, int out_size, void* d_ws, size_t ws_size,
                              hipStream_t stream) {
    const float* x  = (const float*)d_in[0];
    const float* wq = (const float*)d_in[1];
    const float* wk = (const float*)d_in[2];
    const float* wv = (const float*)d_in[3];
    float* out = (float*)d_out;

    char* ws = (char*)d_ws;
    float* Q    = (float*)(ws);
    float* K    = (float*)(ws + 131072);
    int*   idx  = (int*)  (ws + 262144);
    int*   rep  = (int*)  (ws + 327680);
    int*   list = (int*)  (ws + 393216);
    int*   cnt  = (int*)  (ws + 458752);

    qk_kernel<<<BT, 256, 0, stream>>>(x, wq, wk, Q, K);
    init_rep_kernel<<<BT / 256, 256, 0, stream>>>(rep, cnt);
    argmax_kernel<<<4096, 256, 0, stream>>>(Q, K, idx, rep, list, cnt);
    vrow_kernel<<<2048, 256, 0, stream>>>(x, wv, rep, list, cnt, out);
    gather_kernel<<<BT, 256, 0, stream>>>(idx, rep, out);
}

// Round 3
// 228.514 us; speedup vs baseline: 1.8204x; 1.0617x over previous
//
#include <hip/hip_runtime.h>
#include <math.h>

#define TT 4096
#define DM 1024
#define BB 4
#define BT (BB * TT)
#define SENTINEL 0x7fffffff

// ws layout (bytes):
//   Q    : float[BT*2]  @ 0        (131072)
//   K    : float[BT*2]  @ 131072   (131072)  (interleaved k0,k1 pairs)
//   idx  : int[BT]      @ 262144   (65536)
//   rep  : int[BT]      @ 327680   (65536)
//   list : int[BT]      @ 393216   (65536)
//   cnt  : int          @ 458752   (4)

__device__ __forceinline__ float dot4(const float4 a, const float4 b) {
    return a.x * b.x + a.y * b.y + a.z * b.z + a.w * b.w;
}

// ---------- Kernel 1: Q,K projection. 4 rows per block, wave-per-row, weights in LDS.
//            Also initializes rep[] and cnt (saves a launch). ----------
__global__ __launch_bounds__(256) void qk_kernel(const float* __restrict__ x,
                                                 const float* __restrict__ wq,
                                                 const float* __restrict__ wk,
                                                 float* __restrict__ Q,
                                                 float* __restrict__ K,
                                                 int* __restrict__ rep,
                                                 int* __restrict__ cnt) {
    __shared__ float4 wqs0[256], wqs1[256], wks0[256], wks1[256];   // 16 KB
    const int tid = threadIdx.x;
    const int row0 = blockIdx.x * 4;

    wqs0[tid] = ((const float4*)(wq))[tid];
    wqs1[tid] = ((const float4*)(wq + DM))[tid];
    wks0[tid] = ((const float4*)(wk))[tid];
    wks1[tid] = ((const float4*)(wk + DM))[tid];

    // fold rep/cnt init in
    if (tid < 4) rep[row0 + tid] = SENTINEL;
    if (blockIdx.x == 0 && tid == 4) cnt[0] = 0;
    __syncthreads();

    const int wave = tid >> 6, lane = tid & 63;
    const int row = row0 + wave;
    const float4* xr = (const float4*)(x + (size_t)row * DM);

    float s0 = 0.f, s1 = 0.f, s2 = 0.f, s3 = 0.f;
    #pragma unroll
    for (int j = 0; j < 4; ++j) {
        const float4 xv = xr[j * 64 + lane];
        s0 += dot4(xv, wqs0[j * 64 + lane]);
        s1 += dot4(xv, wqs1[j * 64 + lane]);
        s2 += dot4(xv, wks0[j * 64 + lane]);
        s3 += dot4(xv, wks1[j * 64 + lane]);
    }
    #pragma unroll
    for (int off = 32; off > 0; off >>= 1) {
        s0 += __shfl_down(s0, off);
        s1 += __shfl_down(s1, off);
        s2 += __shfl_down(s2, off);
        s3 += __shfl_down(s3, off);
    }
    if (lane == 0) {
        ((float2*)Q)[row] = make_float2(s0, s1);
        ((float2*)K)[row] = make_float2(s2, s3);
    }
}

// ---------- Kernel 2: causal argmax. Wave-per-t, 4x-unrolled lane-strided scan,
//            LDS filled only up to the block's t_max. ----------
__global__ __launch_bounds__(256) void argmax_kernel(const float* __restrict__ Q,
                                                     const float* __restrict__ K,
                                                     int* __restrict__ idx,
                                                     int* __restrict__ rep,
                                                     int* __restrict__ list,
                                                     int* __restrict__ cnt) {
    __shared__ float2 ks[TT];   // 32 KB
    const int b  = blockIdx.x >> 10;
    const int tg = blockIdx.x & 1023;
    const int tid = threadIdx.x;
    const int nfill = tg * 4 + 4;       // only need s <= t_max = tg*4+3

    const float2* kb = (const float2*)(K + (size_t)b * TT * 2);
    for (int i = tid; i < nfill; i += 256) ks[i] = kb[i];
    __syncthreads();

    const int wave = tid >> 6, lane = tid & 63;
    const int t = tg * 4 + wave;
    const float2 q = ((const float2*)Q)[b * TT + t];

    float best = -INFINITY;
    int bi = 0x7fffffff;
    int s = lane;
    // 4 independent LDS reads in flight; in-lane ascending order + strict '>'
    while (s + 192 <= t) {
        const float2 k0 = ks[s];
        const float2 k1 = ks[s + 64];
        const float2 k2 = ks[s + 128];
        const float2 k3 = ks[s + 192];
        const float c0 = q.x * k0.x + q.y * k0.y;
        const float c1 = q.x * k1.x + q.y * k1.y;
        const float c2 = q.x * k2.x + q.y * k2.y;
        const float c3 = q.x * k3.x + q.y * k3.y;
        if (c0 > best) { best = c0; bi = s; }
        if (c1 > best) { best = c1; bi = s + 64; }
        if (c2 > best) { best = c2; bi = s + 128; }
        if (c3 > best) { best = c3; bi = s + 192; }
        s += 256;
    }
    while (s <= t) {
        const float2 kv = ks[s];
        const float sc = q.x * kv.x + q.y * kv.y;
        if (sc > best) { best = sc; bi = s; }
        s += 64;
    }
    // cross-lane argmax, first-occurrence tie-break
    #pragma unroll
    for (int off = 32; off > 0; off >>= 1) {
        const float ov = __shfl_down(best, off);
        const int   oi = __shfl_down(bi, off);
        if (ov > best || (ov == best && oi < bi)) { best = ov; bi = oi; }
    }
    if (lane == 0) {
        idx[b * TT + t] = bi;
        const int old = atomicMin(&rep[b * TT + bi], t);
        if (old == SENTINEL) {
            const int p = atomicAdd(cnt, 1);
            list[p] = b * TT + bi;
        }
    }
}

// ---------- Kernel 3: V-rows, W_V stationary in registers.
//            block = (4-row W_V slice) x (unique-subset); wave owns one output row. ----------
__global__ __launch_bounds__(256) void vrow_kernel(const float* __restrict__ x,
                                                   const float* __restrict__ wv,
                                                   const int* __restrict__ rep,
                                                   const int* __restrict__ list,
                                                   const int* __restrict__ cnt,
                                                   float* __restrict__ out) {
    const int tid = threadIdx.x, wave = tid >> 6, lane = tid & 63;
    const int slice = blockIdx.x >> 3;     // [0,256) -> W_V rows slice*4 .. slice*4+3
    const int usub  = blockIdx.x & 7;
    const int e = slice * 4 + wave;        // output element owned by this wave

    const float4* wrow = (const float4*)(wv + (size_t)e * DM);
    const float4 w0 = wrow[lane];
    const float4 w1 = wrow[lane + 64];
    const float4 w2 = wrow[lane + 128];
    const float4 w3 = wrow[lane + 192];

    const int n = cnt[0];
    for (int li = usub; li < n; li += 8) {
        const int bs = list[li];
        const int b  = bs >> 12;
        const int r  = rep[bs];
        const float4* xr = (const float4*)(x + (size_t)bs * DM);
        const float4 x0 = xr[lane];
        const float4 x1 = xr[lane + 64];
        const float4 x2 = xr[lane + 128];
        const float4 x3 = xr[lane + 192];

        float sum = dot4(w0, x0) + dot4(w1, x1) + dot4(w2, x2) + dot4(w3, x3);
        #pragma unroll
        for (int off = 32; off > 0; off >>= 1) sum += __shfl_down(sum, off);
        if (lane == 0) out[((size_t)(b * TT + r)) * DM + e] = sum;
    }
}

// ---------- Kernel 4: broadcast representative rows to all t ----------
__global__ __launch_bounds__(256) void gather_kernel(const int* __restrict__ idx,
                                                     const int* __restrict__ rep,
                                                     float* __restrict__ out) {
    const int bt = blockIdx.x;
    const int b = bt >> 12, t = bt & (TT - 1);
    const int s = idx[bt];
    const int r = rep[b * TT + s];
    if (r == t) return;
    const float4* src = (const float4*)(out + ((size_t)(b * TT + r)) * DM);
    float4* dst = (float4*)(out + (size_t)bt * DM);
    dst[threadIdx.x] = src[threadIdx.x];
}

extern "C" void kernel_launch(void* const* d_in, const int* in_sizes, int n_in,
                              void* d_out, int out_size, void* d_ws, size_t ws_size,
                              hipStream_t stream) {
    const float* x  = (const float*)d_in[0];
    const float* wq = (const float*)d_in[1];
    const float* wk = (const float*)d_in[2];
    const float* wv = (const float*)d_in[3];
    float* out = (float*)d_out;

    char* ws = (char*)d_ws;
    float* Q    = (float*)(ws);
    float* K    = (float*)(ws + 131072);
    int*   idx  = (int*)  (ws + 262144);
    int*   rep  = (int*)  (ws + 327680);
    int*   list = (int*)  (ws + 393216);
    int*   cnt  = (int*)  (ws + 458752);

    qk_kernel<<<BT / 4, 256, 0, stream>>>(x, wq, wk, Q, K, rep, cnt);
    argmax_kernel<<<4096, 256, 0, stream>>>(Q, K, idx, rep, list, cnt);
    vrow_kernel<<<2048, 256, 0, stream>>>(x, wv, rep, list, cnt, out);
    gather_kernel<<<BT, 256, 0, stream>>>(idx, rep, out);
}

// Round 4
// 215.546 us; speedup vs baseline: 1.9299x; 1.0602x over previous
//
#include <hip/hip_runtime.h>
#include <math.h>

#define TT 4096
#define DM 1024
#define BB 4
#define BT (BB * TT)
#define SENTINEL 0x7fffffff

// ws layout (bytes):
//   Q    : float[BT*2]  @ 0        (131072)
//   K    : float[BT*2]  @ 131072   (131072)  (interleaved k0,k1 pairs)
//   idx  : int[BT]      @ 262144   (65536)
//   rep  : int[BT]      @ 327680   (65536)
//   list : int[BT]      @ 393216   (65536)
//   cnt  : int          @ 458752   (4)

__device__ __forceinline__ float dot4(const float4 a, const float4 b) {
    return a.x * b.x + a.y * b.y + a.z * b.z + a.w * b.w;
}

// ---------- Kernel 1: Q,K projection. 4 rows per block, wave-per-row, weights in LDS.
//            Also initializes rep[] and cnt. ----------
__global__ __launch_bounds__(256) void qk_kernel(const float* __restrict__ x,
                                                 const float* __restrict__ wq,
                                                 const float* __restrict__ wk,
                                                 float* __restrict__ Q,
                                                 float* __restrict__ K,
                                                 int* __restrict__ rep,
                                                 int* __restrict__ cnt) {
    __shared__ float4 wqs0[256], wqs1[256], wks0[256], wks1[256];   // 16 KB
    const int tid = threadIdx.x;
    const int row0 = blockIdx.x * 4;

    wqs0[tid] = ((const float4*)(wq))[tid];
    wqs1[tid] = ((const float4*)(wq + DM))[tid];
    wks0[tid] = ((const float4*)(wk))[tid];
    wks1[tid] = ((const float4*)(wk + DM))[tid];

    if (tid < 4) rep[row0 + tid] = SENTINEL;
    if (blockIdx.x == 0 && tid == 4) cnt[0] = 0;
    __syncthreads();

    const int wave = tid >> 6, lane = tid & 63;
    const int row = row0 + wave;
    const float4* xr = (const float4*)(x + (size_t)row * DM);

    float s0 = 0.f, s1 = 0.f, s2 = 0.f, s3 = 0.f;
    #pragma unroll
    for (int j = 0; j < 4; ++j) {
        const float4 xv = xr[j * 64 + lane];
        s0 += dot4(xv, wqs0[j * 64 + lane]);
        s1 += dot4(xv, wqs1[j * 64 + lane]);
        s2 += dot4(xv, wks0[j * 64 + lane]);
        s3 += dot4(xv, wks1[j * 64 + lane]);
    }
    #pragma unroll
    for (int off = 32; off > 0; off >>= 1) {
        s0 += __shfl_down(s0, off);
        s1 += __shfl_down(s1, off);
        s2 += __shfl_down(s2, off);
        s3 += __shfl_down(s3, off);
    }
    if (lane == 0) {
        ((float2*)Q)[row] = make_float2(s0, s1);
        ((float2*)K)[row] = make_float2(s2, s3);
    }
}

// ---------- Kernel 2: causal argmax. Wave-per-t; float4 LDS reads = 2 points each,
//            2 reads in flight (4 points per unrolled iter). ----------
__global__ __launch_bounds__(256) void argmax_kernel(const float* __restrict__ Q,
                                                     const float* __restrict__ K,
                                                     int* __restrict__ idx,
                                                     int* __restrict__ rep,
                                                     int* __restrict__ list,
                                                     int* __restrict__ cnt) {
    __shared__ float2 ks[TT];   // 32 KB
    const int b  = blockIdx.x >> 10;
    const int tg = blockIdx.x & 1023;
    const int tid = threadIdx.x;
    const int nfill = tg * 4 + 4;       // points 0..t_max

    const float2* kb = (const float2*)(K + (size_t)b * TT * 2);
    for (int i = tid; i < nfill; i += 256) ks[i] = kb[i];
    __syncthreads();

    const int wave = tid >> 6, lane = tid & 63;
    const int t = tg * 4 + wave;
    const float2 q = ((const float2*)Q)[b * TT + t];
    const float4* kp = (const float4*)ks;   // pair p -> points 2p, 2p+1

    float best = -INFINITY;
    int bi = 0x7fffffff;
    int p = lane;
    // main: both pairs fully in range; in-lane ascending s order + strict '>'
    while (2 * (p + 64) + 1 <= t) {
        const float4 a = kp[p];
        const float4 c = kp[p + 64];
        const float c0 = q.x * a.x + q.y * a.y;
        const float c1 = q.x * a.z + q.y * a.w;
        const float c2 = q.x * c.x + q.y * c.y;
        const float c3 = q.x * c.z + q.y * c.w;
        if (c0 > best) { best = c0; bi = 2 * p; }
        if (c1 > best) { best = c1; bi = 2 * p + 1; }
        if (c2 > best) { best = c2; bi = 2 * (p + 64); }
        if (c3 > best) { best = c3; bi = 2 * (p + 64) + 1; }
        p += 128;
    }
    while (2 * p <= t) {
        const float4 a = kp[p];
        const float c0 = q.x * a.x + q.y * a.y;
        if (c0 > best) { best = c0; bi = 2 * p; }
        if (2 * p + 1 <= t) {
            const float c1 = q.x * a.z + q.y * a.w;
            if (c1 > best) { best = c1; bi = 2 * p + 1; }
        }
        p += 64;
    }
    // cross-lane argmax, first-occurrence tie-break (smaller index wins on equal)
    #pragma unroll
    for (int off = 32; off > 0; off >>= 1) {
        const float ov = __shfl_down(best, off);
        const int   oi = __shfl_down(bi, off);
        if (ov > best || (ov == best && oi < bi)) { best = ov; bi = oi; }
    }
    if (lane == 0) {
        idx[b * TT + t] = bi;
        const int old = atomicMin(&rep[b * TT + bi], t);
        if (old == SENTINEL) {
            const int pp = atomicAdd(cnt, 1);
            list[pp] = b * TT + bi;
        }
    }
}

// ---------- Kernel 3: V-rows. 64 slices x 16 cols; wave owns 4 cols in 64 VGPRs;
//            16-way usub split over unique rows. ----------
__global__ __launch_bounds__(256) void vrow_kernel(const float* __restrict__ x,
                                                   const float* __restrict__ wv,
                                                   const int* __restrict__ rep,
                                                   const int* __restrict__ list,
                                                   const int* __restrict__ cnt,
                                                   float* __restrict__ out) {
    const int tid = threadIdx.x, wave = tid >> 6, lane = tid & 63;
    const int slice = blockIdx.x >> 4;     // [0,64): W_V rows slice*16 .. slice*16+15
    const int usub  = blockIdx.x & 15;
    const int e0 = slice * 16 + wave * 4;  // 4 output elements owned by this wave

    float4 w[4][4];
    #pragma unroll
    for (int r = 0; r < 4; ++r) {
        const float4* wr = (const float4*)(wv + (size_t)(e0 + r) * DM);
        #pragma unroll
        for (int j = 0; j < 4; ++j) w[r][j] = wr[j * 64 + lane];
    }

    const int n = cnt[0];
    for (int li = usub; li < n; li += 16) {
        const int bs = list[li];
        const int b  = bs >> 12;
        const int r  = rep[bs];
        const float4* xr = (const float4*)(x + (size_t)bs * DM);
        float4 xv[4];
        #pragma unroll
        for (int j = 0; j < 4; ++j) xv[j] = xr[j * 64 + lane];

        float s0 = 0.f, s1 = 0.f, s2 = 0.f, s3 = 0.f;
        #pragma unroll
        for (int j = 0; j < 4; ++j) {
            s0 += dot4(w[0][j], xv[j]);
            s1 += dot4(w[1][j], xv[j]);
            s2 += dot4(w[2][j], xv[j]);
            s3 += dot4(w[3][j], xv[j]);
        }
        #pragma unroll
        for (int off = 32; off > 0; off >>= 1) {
            s0 += __shfl_down(s0, off);
            s1 += __shfl_down(s1, off);
            s2 += __shfl_down(s2, off);
            s3 += __shfl_down(s3, off);
        }
        if (lane == 0)
            *(float4*)(out + ((size_t)(b * TT + r)) * DM + e0) = make_float4(s0, s1, s2, s3);
    }
}

// ---------- Kernel 4: broadcast representative rows to all t ----------
__global__ __launch_bounds__(256) void gather_kernel(const int* __restrict__ idx,
                                                     const int* __restrict__ rep,
                                                     float* __restrict__ out) {
    const int bt = blockIdx.x;
    const int b = bt >> 12, t = bt & (TT - 1);
    const int s = idx[bt];
    const int r = rep[b * TT + s];
    if (r == t) return;
    const float4* src = (const float4*)(out + ((size_t)(b * TT + r)) * DM);
    float4* dst = (float4*)(out + (size_t)bt * DM);
    dst[threadIdx.x] = src[threadIdx.x];
}

extern "C" void kernel_launch(void* const* d_in, const int* in_sizes, int n_in,
                              void* d_out, int out_size, void* d_ws, size_t ws_size,
                              hipStream_t stream) {
    const float* x  = (const float*)d_in[0];
    const float* wq = (const float*)d_in[1];
    const float* wk = (const float*)d_in[2];
    const float* wv = (const float*)d_in[3];
    float* out = (float*)d_out;

    char* ws = (char*)d_ws;
    float* Q    = (float*)(ws);
    float* K    = (float*)(ws + 131072);
    int*   idx  = (int*)  (ws + 262144);
    int*   rep  = (int*)  (ws + 327680);
    int*   list = (int*)  (ws + 393216);
    int*   cnt  = (int*)  (ws + 458752);

    qk_kernel<<<BT / 4, 256, 0, stream>>>(x, wq, wk, Q, K, rep, cnt);
    argmax_kernel<<<4096, 256, 0, stream>>>(Q, K, idx, rep, list, cnt);
    vrow_kernel<<<1024, 256, 0, stream>>>(x, wv, rep, list, cnt, out);
    gather_kernel<<<BT, 256, 0, stream>>>(idx, rep, out);
}